// Round 12
// baseline (133.904 us; speedup 1.0000x reference)
//
#include <hip/hip_runtime.h>
#include <hip/hip_bf16.h>
#include <stdint.h>

#define NP 4096
#define DF 512
#define NQ3 1536   // 3*DF

using bf16x8 = __attribute__((ext_vector_type(8))) short;
using f32x4  = __attribute__((ext_vector_type(4))) float;

static __device__ __forceinline__ f32x4 mfma16(bf16x8 a, bf16x8 b, f32x4 c) {
    return __builtin_amdgcn_mfma_f32_16x16x32_bf16(a, b, c, 0, 0, 0);
}
static __device__ __forceinline__ f32x4 zero4() { f32x4 z = {0.f,0.f,0.f,0.f}; return z; }

// element-index XOR swizzle for [64][64] bf16 tiles
static __device__ __forceinline__ int SWZ64(int row, int col) {
    return (row * 64 + col) ^ ((row & 7) << 3);
}

static __device__ __forceinline__ unsigned short f2bf(float f) {
    __hip_bfloat16 h = __float2bfloat16(f);
    return reinterpret_cast<unsigned short&>(h);
}

#define GLOAD_LDS16(gp, lp) __builtin_amdgcn_global_load_lds( \
    (const __attribute__((address_space(1))) uint32_t*)(gp), \
    (__attribute__((address_space(3))) uint32_t*)(lp), 16, 0, 0)

// ---- streaming fp32 -> bf16 conversion of x, w_qkv, proj_w (grid-stride) ----
__global__ void convert_all(const float* __restrict__ x,
                            const float* __restrict__ wqkv,
                            const float* __restrict__ projw,
                            unsigned short* __restrict__ xb,
                            unsigned short* __restrict__ wqb,
                            unsigned short* __restrict__ pwb) {
    const int XQ = (8 * NP * DF) / 4;        // 4,194,304 quads
    const int WQ = (3 * DF * DF) / 4;        //   196,608
    const int PQ = (DF * DF) / 4;            //    65,536
    const int TOT = XQ + WQ + PQ;            // 4,456,448
    for (int i = blockIdx.x * blockDim.x + threadIdx.x; i < TOT;
         i += gridDim.x * blockDim.x) {
        const float* src; unsigned short* dst; int j;
        if (i < XQ)           { src = x;     dst = xb;  j = i; }
        else if (i < XQ + WQ) { src = wqkv;  dst = wqb; j = i - XQ; }
        else                  { src = projw; dst = pwb; j = i - XQ - WQ; }
        float4 v = *(const float4*)(src + (size_t)j * 4);
        ushort4 o;
        o.x = f2bf(v.x); o.y = f2bf(v.y); o.z = f2bf(v.z); o.w = f2bf(v.w);
        *(ushort4*)(dst + (size_t)j * 4) = o;
    }
}

// ==== K2: qkv = xb @ wqb^T   (M=32768, N=1536, K=512, bf16 out) ====
// m97-style 128x128 tile, 4 waves, gload_lds staging, swizzled LDS.
// (256,4): 4 blocks/CU — same reg profile as proj_gemm which holds it spill-free.
__launch_bounds__(256, 4)
__global__ void qkv_gemm(const __hip_bfloat16* __restrict__ A,   // [32768][512]
                         const __hip_bfloat16* __restrict__ Bt,  // [1536][512]
                         unsigned short* __restrict__ C) {       // [32768][1536]
    __shared__ __hip_bfloat16 As[128 * 64];   // 16 KB, chunk-swizzled
    __shared__ __hip_bfloat16 Bs[128 * 64];

    const int tid  = threadIdx.x;
    const int wid  = tid >> 6;
    const int lane = tid & 63;
    const int ln16 = lane & 15;
    const int lg   = lane >> 4;
    const int wr   = wid >> 1;
    const int wc   = wid & 1;

    // XCD-chunked work swizzle: 3072 blocks, 8 XCDs, 384 per XCD, nb-inner.
    int wk = (blockIdx.x & 7) * 384 + (blockIdx.x >> 3);
    const int m0 = (wk / 12) * 128;
    const int n0 = (wk % 12) * 128;

    f32x4 acc[4][4];
    #pragma unroll
    for (int i = 0; i < 4; ++i)
        #pragma unroll
        for (int j = 0; j < 4; ++j) acc[i][j] = zero4();

    for (int kt = 0; kt < 8; ++kt) {
        int k0 = kt * 64;
        #pragma unroll
        for (int it = 0; it < 4; ++it) {
            int slot = it * 256 + tid;          // 1024 chunks of 16B
            int row  = slot >> 3;               // 8 chunks per row
            int c    = slot & 7;
            int gc   = (c ^ (row & 7)) * 8;     // pre-swizzled source
            GLOAD_LDS16(A  + (size_t)(m0 + row) * DF + k0 + gc, &As[slot * 8]);
            GLOAD_LDS16(Bt + (size_t)(n0 + row) * DF + k0 + gc, &Bs[slot * 8]);
        }
        __syncthreads();
        #pragma unroll
        for (int kk = 0; kk < 2; ++kk) {
            int c0 = kk * 4 + lg;
            bf16x8 af[4], bfr[4];
            #pragma unroll
            for (int rt = 0; rt < 4; ++rt) {
                int r = wr * 64 + rt * 16 + ln16;
                af[rt] = *(const bf16x8*)&As[(r << 6) + ((c0 ^ (r & 7)) << 3)];
            }
            #pragma unroll
            for (int ct = 0; ct < 4; ++ct) {
                int r = wc * 64 + ct * 16 + ln16;
                bfr[ct] = *(const bf16x8*)&Bs[(r << 6) + ((c0 ^ (r & 7)) << 3)];
            }
            #pragma unroll
            for (int rt = 0; rt < 4; ++rt)
                #pragma unroll
                for (int ct = 0; ct < 4; ++ct)
                    acc[rt][ct] = mfma16(af[rt], bfr[ct], acc[rt][ct]);
        }
        __syncthreads();
    }

    #pragma unroll
    for (int rt = 0; rt < 4; ++rt)
        #pragma unroll
        for (int ct = 0; ct < 4; ++ct)
            #pragma unroll
            for (int j = 0; j < 4; ++j)
                C[(size_t)(m0 + wr * 64 + rt * 16 + lg * 4 + j) * NQ3
                  + n0 + wc * 64 + ct * 16 + ln16] = f2bf(acc[rt][ct][j]);
}

// ==== K3: windowed attention. One wave = one (head, window). No barriers. ====
__launch_bounds__(256, 2)
__global__ void attn(const __hip_bfloat16* __restrict__ qkv,   // [32768][1536]
                     unsigned short* __restrict__ aout) {      // [32768][512]
    // per wave: [0] = P (64x64), [1] = V^T (64x64); wave-private -> no syncs
    __shared__ unsigned short lds[4][2][64 * 64];   // 64 KB

    const int tid  = threadIdx.x;
    const int wid  = tid >> 6;
    const int lane = tid & 63;
    const int ln16 = lane & 15;
    const int lg   = lane >> 4;

    const int blk = blockIdx.x;          // 1024 = (b*64+w)*2 + half
    const int bw  = blk >> 1;
    const int hh  = (blk & 1) * 4 + wid; // head 0..7
    const size_t tokbase = (size_t)bw * 64;
    const __hip_bfloat16* base = qkv + tokbase * NQ3;

    // ---- V -> V^T in LDS (coalesced global reads, swizzled scalar writes) ----
    #pragma unroll
    for (int rt = 0; rt < 4; ++rt)
        #pragma unroll
        for (int ks = 0; ks < 2; ++ks) {
            bf16x8 vf = *(const bf16x8*)(base + (size_t)(rt * 16 + ln16) * NQ3
                                         + 2 * DF + hh * 64 + ks * 32 + lg * 8);
            #pragma unroll
            for (int i = 0; i < 8; ++i) {
                int d = ks * 32 + lg * 8 + i;
                lds[wid][1][SWZ64(d, rt * 16 + ln16)] = (unsigned short)vf[i];
            }
        }

    // ---- K fragments (held in regs across the S phase) ----
    bf16x8 kf[4][2];
    #pragma unroll
    for (int ct = 0; ct < 4; ++ct)
        #pragma unroll
        for (int ks = 0; ks < 2; ++ks)
            kf[ct][ks] = *(const bf16x8*)(base + (size_t)(ct * 16 + ln16) * NQ3
                                          + DF + hh * 64 + ks * 32 + lg * 8);

    // ---- per 16-row strip: S = scale*Q K^T, softmax, P -> LDS ----
    const float scale = 0.125f;
    #pragma unroll
    for (int rt = 0; rt < 4; ++rt) {
        bf16x8 qf[2];
        #pragma unroll
        for (int ks = 0; ks < 2; ++ks)
            qf[ks] = *(const bf16x8*)(base + (size_t)(rt * 16 + ln16) * NQ3
                                      + hh * 64 + ks * 32 + lg * 8);
        f32x4 s[4];
        #pragma unroll
        for (int ct = 0; ct < 4; ++ct) s[ct] = zero4();
        #pragma unroll
        for (int ks = 0; ks < 2; ++ks)
            #pragma unroll
            for (int ct = 0; ct < 4; ++ct)
                s[ct] = mfma16(qf[ks], kf[ct][ks], s[ct]);
        #pragma unroll
        for (int j = 0; j < 4; ++j) {
            float sv[4];
            float m = -1e30f;
            #pragma unroll
            for (int ct = 0; ct < 4; ++ct) { sv[ct] = s[ct][j] * scale; m = fmaxf(m, sv[ct]); }
            #pragma unroll
            for (int off = 1; off < 16; off <<= 1) m = fmaxf(m, __shfl_xor(m, off));
            float pv[4], sum = 0.f;
            #pragma unroll
            for (int ct = 0; ct < 4; ++ct) { pv[ct] = __expf(sv[ct] - m); sum += pv[ct]; }
            #pragma unroll
            for (int off = 1; off < 16; off <<= 1) sum += __shfl_xor(sum, off);
            float inv = 1.f / sum;
            int q = rt * 16 + lg * 4 + j;
            #pragma unroll
            for (int ct = 0; ct < 4; ++ct)
                lds[wid][0][SWZ64(q, ct * 16 + ln16)] = f2bf(pv[ct] * inv);
        }
    }

    // ---- V^T fragments (regs), then O = P V per strip ----
    bf16x8 vtf[4][2];
    #pragma unroll
    for (int ct = 0; ct < 4; ++ct)
        #pragma unroll
        for (int ks = 0; ks < 2; ++ks)
            vtf[ct][ks] = *(const bf16x8*)&lds[wid][1][SWZ64(ct * 16 + ln16,
                                                             ks * 32 + lg * 8)];
    #pragma unroll
    for (int rt = 0; rt < 4; ++rt) {
        bf16x8 pf[2];
        #pragma unroll
        for (int ks = 0; ks < 2; ++ks)
            pf[ks] = *(const bf16x8*)&lds[wid][0][SWZ64(rt * 16 + ln16,
                                                        ks * 32 + lg * 8)];
        f32x4 o[4];
        #pragma unroll
        for (int ct = 0; ct < 4; ++ct) o[ct] = zero4();
        #pragma unroll
        for (int ks = 0; ks < 2; ++ks)
            #pragma unroll
            for (int ct = 0; ct < 4; ++ct)
                o[ct] = mfma16(pf[ks], vtf[ct][ks], o[ct]);
        #pragma unroll
        for (int ct = 0; ct < 4; ++ct)
            #pragma unroll
            for (int j = 0; j < 4; ++j)
                aout[(tokbase + rt * 16 + lg * 4 + j) * DF + hh * 64
                     + ct * 16 + ln16] = f2bf(o[ct][j]);
    }
}

// ==== K4: out = aout @ proj_w^T + bias (128x128 tile, swizzled LDS) ====
__launch_bounds__(256, 4)
__global__ void proj_gemm(const __hip_bfloat16* __restrict__ A,    // [32768][512]
                          const __hip_bfloat16* __restrict__ Bt,   // [512][512]
                          const float* __restrict__ bias,
                          float* __restrict__ out) {
    __shared__ __hip_bfloat16 As[128 * 64];
    __shared__ __hip_bfloat16 Bs[128 * 64];

    const int tid  = threadIdx.x;
    const int wid  = tid >> 6;
    const int lane = tid & 63;
    const int ln16 = lane & 15;
    const int lg   = lane >> 4;
    const int wr   = wid >> 1;
    const int wc   = wid & 1;

    // XCD-chunked swizzle: 1024 blocks -> 128 per XCD, nb-inner
    int wk = (blockIdx.x & 7) * 128 + (blockIdx.x >> 3);
    const int m0  = (wk >> 2) * 128;
    const int n0g = (wk & 3) * 128;

    f32x4 acc[4][4];
    #pragma unroll
    for (int i = 0; i < 4; ++i)
        #pragma unroll
        for (int j = 0; j < 4; ++j) acc[i][j] = zero4();

    for (int kt = 0; kt < 8; ++kt) {
        int k0 = kt * 64;
        #pragma unroll
        for (int it = 0; it < 4; ++it) {
            int slot = it * 256 + tid;
            int row  = slot >> 3;
            int c    = slot & 7;
            int gc   = (c ^ (row & 7)) * 8;
            GLOAD_LDS16(A  + (size_t)(m0  + row) * DF + k0 + gc, &As[slot * 8]);
            GLOAD_LDS16(Bt + (size_t)(n0g + row) * DF + k0 + gc, &Bs[slot * 8]);
        }
        __syncthreads();
        #pragma unroll
        for (int kk = 0; kk < 2; ++kk) {
            int c0 = kk * 4 + lg;
            bf16x8 af[4], bfr[4];
            #pragma unroll
            for (int rt = 0; rt < 4; ++rt) {
                int r = wr * 64 + rt * 16 + ln16;
                af[rt] = *(const bf16x8*)&As[(r << 6) + ((c0 ^ (r & 7)) << 3)];
            }
            #pragma unroll
            for (int ct = 0; ct < 4; ++ct) {
                int r = wc * 64 + ct * 16 + ln16;
                bfr[ct] = *(const bf16x8*)&Bs[(r << 6) + ((c0 ^ (r & 7)) << 3)];
            }
            #pragma unroll
            for (int rt = 0; rt < 4; ++rt)
                #pragma unroll
                for (int ct = 0; ct < 4; ++ct)
                    acc[rt][ct] = mfma16(af[rt], bfr[ct], acc[rt][ct]);
        }
        __syncthreads();
    }

    #pragma unroll
    for (int ct = 0; ct < 4; ++ct) {
        int col = n0g + wc * 64 + ct * 16 + ln16;
        float bv = bias[col];
        #pragma unroll
        for (int rt = 0; rt < 4; ++rt)
            #pragma unroll
            for (int j = 0; j < 4; ++j)
                out[(size_t)(m0 + wr * 64 + rt * 16 + lg * 4 + j) * DF + col] =
                    acc[rt][ct][j] + bv;
    }
}

extern "C" void kernel_launch(void* const* d_in, const int* in_sizes, int n_in,
                              void* d_out, int out_size, void* d_ws, size_t ws_size,
                              hipStream_t stream) {
    const float* x      = (const float*)d_in[0];
    // d_in[1] (z) unused by the reference
    const float* w_qkv  = (const float*)d_in[2];
    const float* proj_w = (const float*)d_in[3];
    const float* proj_b = (const float*)d_in[4];
    float* outp = (float*)d_out;

    const size_t NTOK = (size_t)8 * NP;                 // 32768
    unsigned short* xb   = (unsigned short*)d_ws;       // 32 MB (reused as aout)
    unsigned short* qkvb = xb + NTOK * DF;              // 96 MB
    unsigned short* wqb  = qkvb + NTOK * NQ3;           // 1.5 MB
    unsigned short* pwb  = wqb + 3 * DF * DF;           // 0.5 MB
    unsigned short* aout = xb;                          // xb dead after qkv_gemm

    convert_all<<<2048, 512, 0, stream>>>(x, w_qkv, proj_w, xb, wqb, pwb);

    qkv_gemm<<<3072, 256, 0, stream>>>((const __hip_bfloat16*)xb,
                                       (const __hip_bfloat16*)wqb, qkvb);

    attn<<<1024, 256, 0, stream>>>((const __hip_bfloat16*)qkvb, aout);

    proj_gemm<<<1024, 256, 0, stream>>>((const __hip_bfloat16*)aout,
                                        (const __hip_bfloat16*)pwb,
                                        proj_b, outp);
}

// Round 13
// 131.497 us; speedup vs baseline: 1.0183x; 1.0183x over previous
//
#include <hip/hip_runtime.h>
#include <hip/hip_bf16.h>
#include <stdint.h>

#define NP 4096
#define DF 512
#define NQ3 1536   // 3*DF

using bf16x8 = __attribute__((ext_vector_type(8))) short;
using f32x4  = __attribute__((ext_vector_type(4))) float;

static __device__ __forceinline__ f32x4 mfma16(bf16x8 a, bf16x8 b, f32x4 c) {
    return __builtin_amdgcn_mfma_f32_16x16x32_bf16(a, b, c, 0, 0, 0);
}
static __device__ __forceinline__ f32x4 zero4() { f32x4 z = {0.f,0.f,0.f,0.f}; return z; }

// element-index XOR swizzle for [64][64] bf16 tiles
static __device__ __forceinline__ int SWZ64(int row, int col) {
    return (row * 64 + col) ^ ((row & 7) << 3);
}

static __device__ __forceinline__ unsigned short f2bf(float f) {
    __hip_bfloat16 h = __float2bfloat16(f);
    return reinterpret_cast<unsigned short&>(h);
}

#define GLOAD_LDS16(gp, lp) __builtin_amdgcn_global_load_lds( \
    (const __attribute__((address_space(1))) uint32_t*)(gp), \
    (__attribute__((address_space(3))) uint32_t*)(lp), 16, 0, 0)

// ---- streaming fp32 -> bf16 conversion of x, w_qkv, proj_w (grid-stride) ----
__global__ void convert_all(const float* __restrict__ x,
                            const float* __restrict__ wqkv,
                            const float* __restrict__ projw,
                            unsigned short* __restrict__ xb,
                            unsigned short* __restrict__ wqb,
                            unsigned short* __restrict__ pwb) {
    const int XQ = (8 * NP * DF) / 4;        // 4,194,304 quads
    const int WQ = (3 * DF * DF) / 4;        //   196,608
    const int PQ = (DF * DF) / 4;            //    65,536
    const int TOT = XQ + WQ + PQ;            // 4,456,448
    for (int i = blockIdx.x * blockDim.x + threadIdx.x; i < TOT;
         i += gridDim.x * blockDim.x) {
        const float* src; unsigned short* dst; int j;
        if (i < XQ)           { src = x;     dst = xb;  j = i; }
        else if (i < XQ + WQ) { src = wqkv;  dst = wqb; j = i - XQ; }
        else                  { src = projw; dst = pwb; j = i - XQ - WQ; }
        float4 v = *(const float4*)(src + (size_t)j * 4);
        ushort4 o;
        o.x = f2bf(v.x); o.y = f2bf(v.y); o.z = f2bf(v.z); o.w = f2bf(v.w);
        *(ushort4*)(dst + (size_t)j * 4) = o;
    }
}

// ==== K2: qkv = xb @ wqb^T   (M=32768, N=1536, K=512, bf16 out) ====
// m97-style 128x128 tile, 4 waves, gload_lds staging, swizzled LDS.
// (256,2): 2 blocks/CU is the max spill-free occupancy for this kernel
// (measured: (256,4) spills ~20 MB scratch and regresses 58->69 us).
__launch_bounds__(256, 2)
__global__ void qkv_gemm(const __hip_bfloat16* __restrict__ A,   // [32768][512]
                         const __hip_bfloat16* __restrict__ Bt,  // [1536][512]
                         unsigned short* __restrict__ C) {       // [32768][1536]
    __shared__ __hip_bfloat16 As[128 * 64];   // 16 KB, chunk-swizzled
    __shared__ __hip_bfloat16 Bs[128 * 64];

    const int tid  = threadIdx.x;
    const int wid  = tid >> 6;
    const int lane = tid & 63;
    const int ln16 = lane & 15;
    const int lg   = lane >> 4;
    const int wr   = wid >> 1;
    const int wc   = wid & 1;

    // XCD-chunked work swizzle: 3072 blocks, 8 XCDs, 384 per XCD, nb-inner.
    int wk = (blockIdx.x & 7) * 384 + (blockIdx.x >> 3);
    const int m0 = (wk / 12) * 128;
    const int n0 = (wk % 12) * 128;

    f32x4 acc[4][4];
    #pragma unroll
    for (int i = 0; i < 4; ++i)
        #pragma unroll
        for (int j = 0; j < 4; ++j) acc[i][j] = zero4();

    for (int kt = 0; kt < 8; ++kt) {
        int k0 = kt * 64;
        #pragma unroll
        for (int it = 0; it < 4; ++it) {
            int slot = it * 256 + tid;          // 1024 chunks of 16B
            int row  = slot >> 3;               // 8 chunks per row
            int c    = slot & 7;
            int gc   = (c ^ (row & 7)) * 8;     // pre-swizzled source
            GLOAD_LDS16(A  + (size_t)(m0 + row) * DF + k0 + gc, &As[slot * 8]);
            GLOAD_LDS16(Bt + (size_t)(n0 + row) * DF + k0 + gc, &Bs[slot * 8]);
        }
        __syncthreads();
        #pragma unroll
        for (int kk = 0; kk < 2; ++kk) {
            int c0 = kk * 4 + lg;
            bf16x8 af[4], bfr[4];
            #pragma unroll
            for (int rt = 0; rt < 4; ++rt) {
                int r = wr * 64 + rt * 16 + ln16;
                af[rt] = *(const bf16x8*)&As[(r << 6) + ((c0 ^ (r & 7)) << 3)];
            }
            #pragma unroll
            for (int ct = 0; ct < 4; ++ct) {
                int r = wc * 64 + ct * 16 + ln16;
                bfr[ct] = *(const bf16x8*)&Bs[(r << 6) + ((c0 ^ (r & 7)) << 3)];
            }
            #pragma unroll
            for (int rt = 0; rt < 4; ++rt)
                #pragma unroll
                for (int ct = 0; ct < 4; ++ct)
                    acc[rt][ct] = mfma16(af[rt], bfr[ct], acc[rt][ct]);
        }
        __syncthreads();
    }

    #pragma unroll
    for (int rt = 0; rt < 4; ++rt)
        #pragma unroll
        for (int ct = 0; ct < 4; ++ct)
            #pragma unroll
            for (int j = 0; j < 4; ++j)
                C[(size_t)(m0 + wr * 64 + rt * 16 + lg * 4 + j) * NQ3
                  + n0 + wc * 64 + ct * 16 + ln16] = f2bf(acc[rt][ct][j]);
}

// ==== K3: windowed attention. One wave = one (head, window). No barriers. ====
__launch_bounds__(256, 2)
__global__ void attn(const __hip_bfloat16* __restrict__ qkv,   // [32768][1536]
                     unsigned short* __restrict__ aout) {      // [32768][512]
    // per wave: [0] = P (64x64), [1] = V^T (64x64); wave-private -> no syncs
    __shared__ unsigned short lds[4][2][64 * 64];   // 64 KB

    const int tid  = threadIdx.x;
    const int wid  = tid >> 6;
    const int lane = tid & 63;
    const int ln16 = lane & 15;
    const int lg   = lane >> 4;

    const int blk = blockIdx.x;          // 1024 = (b*64+w)*2 + half
    const int bw  = blk >> 1;
    const int hh  = (blk & 1) * 4 + wid; // head 0..7
    const size_t tokbase = (size_t)bw * 64;
    const __hip_bfloat16* base = qkv + tokbase * NQ3;

    // ---- V -> V^T in LDS (coalesced global reads, swizzled scalar writes) ----
    #pragma unroll
    for (int rt = 0; rt < 4; ++rt)
        #pragma unroll
        for (int ks = 0; ks < 2; ++ks) {
            bf16x8 vf = *(const bf16x8*)(base + (size_t)(rt * 16 + ln16) * NQ3
                                         + 2 * DF + hh * 64 + ks * 32 + lg * 8);
            #pragma unroll
            for (int i = 0; i < 8; ++i) {
                int d = ks * 32 + lg * 8 + i;
                lds[wid][1][SWZ64(d, rt * 16 + ln16)] = (unsigned short)vf[i];
            }
        }

    // ---- K fragments (held in regs across the S phase) ----
    bf16x8 kf[4][2];
    #pragma unroll
    for (int ct = 0; ct < 4; ++ct)
        #pragma unroll
        for (int ks = 0; ks < 2; ++ks)
            kf[ct][ks] = *(const bf16x8*)(base + (size_t)(ct * 16 + ln16) * NQ3
                                          + DF + hh * 64 + ks * 32 + lg * 8);

    // ---- per 16-row strip: S = scale*Q K^T, softmax, P -> LDS ----
    const float scale = 0.125f;
    #pragma unroll
    for (int rt = 0; rt < 4; ++rt) {
        bf16x8 qf[2];
        #pragma unroll
        for (int ks = 0; ks < 2; ++ks)
            qf[ks] = *(const bf16x8*)(base + (size_t)(rt * 16 + ln16) * NQ3
                                      + hh * 64 + ks * 32 + lg * 8);
        f32x4 s[4];
        #pragma unroll
        for (int ct = 0; ct < 4; ++ct) s[ct] = zero4();
        #pragma unroll
        for (int ks = 0; ks < 2; ++ks)
            #pragma unroll
            for (int ct = 0; ct < 4; ++ct)
                s[ct] = mfma16(qf[ks], kf[ct][ks], s[ct]);
        #pragma unroll
        for (int j = 0; j < 4; ++j) {
            float sv[4];
            float m = -1e30f;
            #pragma unroll
            for (int ct = 0; ct < 4; ++ct) { sv[ct] = s[ct][j] * scale; m = fmaxf(m, sv[ct]); }
            #pragma unroll
            for (int off = 1; off < 16; off <<= 1) m = fmaxf(m, __shfl_xor(m, off));
            float pv[4], sum = 0.f;
            #pragma unroll
            for (int ct = 0; ct < 4; ++ct) { pv[ct] = __expf(sv[ct] - m); sum += pv[ct]; }
            #pragma unroll
            for (int off = 1; off < 16; off <<= 1) sum += __shfl_xor(sum, off);
            float inv = 1.f / sum;
            int q = rt * 16 + lg * 4 + j;
            #pragma unroll
            for (int ct = 0; ct < 4; ++ct)
                lds[wid][0][SWZ64(q, ct * 16 + ln16)] = f2bf(pv[ct] * inv);
        }
    }

    // ---- V^T fragments (regs), then O = P V per strip ----
    bf16x8 vtf[4][2];
    #pragma unroll
    for (int ct = 0; ct < 4; ++ct)
        #pragma unroll
        for (int ks = 0; ks < 2; ++ks)
            vtf[ct][ks] = *(const bf16x8*)&lds[wid][1][SWZ64(ct * 16 + ln16,
                                                             ks * 32 + lg * 8)];
    #pragma unroll
    for (int rt = 0; rt < 4; ++rt) {
        bf16x8 pf[2];
        #pragma unroll
        for (int ks = 0; ks < 2; ++ks)
            pf[ks] = *(const bf16x8*)&lds[wid][0][SWZ64(rt * 16 + ln16,
                                                        ks * 32 + lg * 8)];
        f32x4 o[4];
        #pragma unroll
        for (int ct = 0; ct < 4; ++ct) o[ct] = zero4();
        #pragma unroll
        for (int ks = 0; ks < 2; ++ks)
            #pragma unroll
            for (int ct = 0; ct < 4; ++ct)
                o[ct] = mfma16(pf[ks], vtf[ct][ks], o[ct]);
        #pragma unroll
        for (int ct = 0; ct < 4; ++ct)
            #pragma unroll
            for (int j = 0; j < 4; ++j)
                aout[(tokbase + rt * 16 + lg * 4 + j) * DF + hh * 64
                     + ct * 16 + ln16] = f2bf(o[ct][j]);
    }
}

// ==== K4: out = aout @ proj_w^T + bias (128x128 tile, swizzled LDS) ====
__launch_bounds__(256, 4)
__global__ void proj_gemm(const __hip_bfloat16* __restrict__ A,    // [32768][512]
                          const __hip_bfloat16* __restrict__ Bt,   // [512][512]
                          const float* __restrict__ bias,
                          float* __restrict__ out) {
    __shared__ __hip_bfloat16 As[128 * 64];
    __shared__ __hip_bfloat16 Bs[128 * 64];

    const int tid  = threadIdx.x;
    const int wid  = tid >> 6;
    const int lane = tid & 63;
    const int ln16 = lane & 15;
    const int lg   = lane >> 4;
    const int wr   = wid >> 1;
    const int wc   = wid & 1;

    // XCD-chunked swizzle: 1024 blocks -> 128 per XCD, nb-inner
    int wk = (blockIdx.x & 7) * 128 + (blockIdx.x >> 3);
    const int m0  = (wk >> 2) * 128;
    const int n0g = (wk & 3) * 128;

    f32x4 acc[4][4];
    #pragma unroll
    for (int i = 0; i < 4; ++i)
        #pragma unroll
        for (int j = 0; j < 4; ++j) acc[i][j] = zero4();

    for (int kt = 0; kt < 8; ++kt) {
        int k0 = kt * 64;
        #pragma unroll
        for (int it = 0; it < 4; ++it) {
            int slot = it * 256 + tid;
            int row  = slot >> 3;
            int c    = slot & 7;
            int gc   = (c ^ (row & 7)) * 8;
            GLOAD_LDS16(A  + (size_t)(m0  + row) * DF + k0 + gc, &As[slot * 8]);
            GLOAD_LDS16(Bt + (size_t)(n0g + row) * DF + k0 + gc, &Bs[slot * 8]);
        }
        __syncthreads();
        #pragma unroll
        for (int kk = 0; kk < 2; ++kk) {
            int c0 = kk * 4 + lg;
            bf16x8 af[4], bfr[4];
            #pragma unroll
            for (int rt = 0; rt < 4; ++rt) {
                int r = wr * 64 + rt * 16 + ln16;
                af[rt] = *(const bf16x8*)&As[(r << 6) + ((c0 ^ (r & 7)) << 3)];
            }
            #pragma unroll
            for (int ct = 0; ct < 4; ++ct) {
                int r = wc * 64 + ct * 16 + ln16;
                bfr[ct] = *(const bf16x8*)&Bs[(r << 6) + ((c0 ^ (r & 7)) << 3)];
            }
            #pragma unroll
            for (int rt = 0; rt < 4; ++rt)
                #pragma unroll
                for (int ct = 0; ct < 4; ++ct)
                    acc[rt][ct] = mfma16(af[rt], bfr[ct], acc[rt][ct]);
        }
        __syncthreads();
    }

    #pragma unroll
    for (int ct = 0; ct < 4; ++ct) {
        int col = n0g + wc * 64 + ct * 16 + ln16;
        float bv = bias[col];
        #pragma unroll
        for (int rt = 0; rt < 4; ++rt)
            #pragma unroll
            for (int j = 0; j < 4; ++j)
                out[(size_t)(m0 + wr * 64 + rt * 16 + lg * 4 + j) * DF + col] =
                    acc[rt][ct][j] + bv;
    }
}

extern "C" void kernel_launch(void* const* d_in, const int* in_sizes, int n_in,
                              void* d_out, int out_size, void* d_ws, size_t ws_size,
                              hipStream_t stream) {
    const float* x      = (const float*)d_in[0];
    // d_in[1] (z) unused by the reference
    const float* w_qkv  = (const float*)d_in[2];
    const float* proj_w = (const float*)d_in[3];
    const float* proj_b = (const float*)d_in[4];
    float* outp = (float*)d_out;

    const size_t NTOK = (size_t)8 * NP;                 // 32768
    unsigned short* xb   = (unsigned short*)d_ws;       // 32 MB (reused as aout)
    unsigned short* qkvb = xb + NTOK * DF;              // 96 MB
    unsigned short* wqb  = qkvb + NTOK * NQ3;           // 1.5 MB
    unsigned short* pwb  = wqb + 3 * DF * DF;           // 0.5 MB
    unsigned short* aout = xb;                          // xb dead after qkv_gemm

    convert_all<<<2048, 512, 0, stream>>>(x, w_qkv, proj_w, xb, wqb, pwb);

    qkv_gemm<<<3072, 256, 0, stream>>>((const __hip_bfloat16*)xb,
                                       (const __hip_bfloat16*)wqb, qkvb);

    attn<<<1024, 256, 0, stream>>>((const __hip_bfloat16*)qkvb, aout);

    proj_gemm<<<1024, 256, 0, stream>>>((const __hip_bfloat16*)aout,
                                        (const __hip_bfloat16*)pwb,
                                        proj_b, outp);
}